// Round 9
// baseline (19.774 us; speedup 1.0000x reference)
//
#include <hip/hip_runtime.h>

// DiscreteLinear: z[b,i] = sum_j weight[a[b],i,j] * x[b,j] + bias[a[b],i]
// B=2048, A=64, D=512.
// R8 = R7 (DMA W-ring, fused bucket, swizzled bf16 Xs) + deeper pipeline:
//  - ring 5 slots (80 KB), prefetch depth 4 steps, steady wait vmcnt(6)
//    (8 DMAs in flight, wait only the oldest step) -> absorbs HBM tail
//    jitter that the depth-3 ring exposed at each lockstep barrier.
//  - steady K loop fully unrolled (12 iters) -> compile-time ring slots.
//  - Xs staging writes guarded by r < rem (cnt~32-48 of 64: skip ~40% of
//    LDS write traffic). Loads stay unconditional+clamped (R4 scratch trap
//    is conditional *definitions*, not conditional stores).
// Budget: 72 MB mandatory HBM @ ~6.5 TB/s ~= 11 us + prologue ~1.3 + launch.

#define NA 64
#define DD 512
#define NB 2048
#define BN 128          // output cols per block
#define NW 8            // waves per block
#define BK 32           // fp32 k per ring step
#define NSTEPS 16       // DD / BK
#define NSLOT 5         // ring slots (depth-4 prefetch)

typedef __bf16  bf16x8  __attribute__((ext_vector_type(8)));
typedef __bf16  bf16x4  __attribute__((ext_vector_type(4)));
typedef float   floatx4 __attribute__((ext_vector_type(4)));

#define GLD16(g, l)                                                         \
  __builtin_amdgcn_global_load_lds(                                         \
      (const __attribute__((address_space(1))) void*)(g),                   \
      (__attribute__((address_space(3))) void*)(l), 16, 0, 0)
#define VMCNT(n) asm volatile("s_waitcnt vmcnt(" #n ")" ::: "memory")
#define LGKMCNT0 asm volatile("s_waitcnt lgkmcnt(0)" ::: "memory")
#define SBAR     __builtin_amdgcn_s_barrier()
#define SCHED0   __builtin_amdgcn_sched_barrier(0)

static __device__ inline bf16x8 cvt8(floatx4 lo, floatx4 hi) {
    bf16x8 r;
    r[0] = (__bf16)lo[0]; r[1] = (__bf16)lo[1];
    r[2] = (__bf16)lo[2]; r[3] = (__bf16)lo[3];
    r[4] = (__bf16)hi[0]; r[5] = (__bf16)hi[1];
    r[6] = (__bf16)hi[2]; r[7] = (__bf16)hi[3];
    return r;
}

__global__ __launch_bounds__(512, 1) void dl_fused(
        const float* __restrict__ x,
        const int*   __restrict__ act,
        const float* __restrict__ weight,
        const float* __restrict__ bias,
        float*       __restrict__ out)
{
    const int a    = blockIdx.x;         // linear id = a + 64*y -> XCD = a%8:
    const int tid  = threadIdx.x;        // the 4 col-tiles of an action share
    const int wave = tid >> 6;           // an XCD -> x/act L2 reuse
    const int lane = tid & 63;
    const int l16  = lane & 15;
    const int kgrp = lane >> 4;
    const int colbase = blockIdx.y * BN;
    const int ncol    = colbase + wave * 16 + l16;

    __shared__ int s_perm[NB];                          // 8 KB
    __shared__ int s_wcnt[NW];
    __shared__ __align__(16) __bf16 Xs[64][DD];         // 64 KB
    __shared__ __align__(16) float  Wl[NSLOT][BN][BK];  // 80 KB ring

    // ---- fused bucket: ballot-compact indices with act[i]==a ----
    const int ibase = wave * (NB / NW);
    int myact[NB / NW / 64];                            // 4, regs
    int wcnt = 0;
#pragma unroll
    for (int it = 0; it < NB / NW / 64; ++it) {
        myact[it] = act[ibase + it * 64 + lane];
        unsigned long long m = __ballot(myact[it] == a);
        wcnt += (int)__popcll(m);
    }
    if (lane == 0) s_wcnt[wave] = wcnt;
    __syncthreads();
    int cnt = 0, off = 0;
#pragma unroll
    for (int v = 0; v < NW; ++v) {
        const int c = s_wcnt[v];
        if (v < wave) off += c;
        cnt += c;
    }
    if (cnt == 0) return;
#pragma unroll
    for (int it = 0; it < NB / NW / 64; ++it) {
        unsigned long long m = __ballot(myact[it] == a);
        if (myact[it] == a) {
            int pos = off + (int)__popcll(m & ((1ull << lane) - 1ull));
            s_perm[pos] = ibase + it * 64 + lane;
        }
        off += (int)__popcll(m);
    }
    __syncthreads();                      // publish s_perm

    const float  bias_v = bias[(size_t)a * DD + ncol];
    const float* wtile  = weight + (size_t)a * DD * DD + (size_t)colbase * DD;

    // DMA source decomposition (per lane): row-chunk swizzle, 16B units.
    const int r8 = lane >> 3;             // row-within-8 group, 0..7
    const int su = ((lane & 7) ^ r8) << 2;// swizzled float offset in 128B chunk
    const int srow = tid >> 5;            // x staging: 0..15
    const int skk  = (tid & 31) << 2;     // 32 lanes x float4 per row

    for (int m0 = 0; m0 < cnt; m0 += 64) {
        const int rem    = min(cnt - m0, 64);
        const int nchunk = (rem + 15) >> 4;

        // ---- (1) issue x loads (OLDER than DMA: consume waits vmcnt(8)) ----
        floatx4 xv[16];
#pragma unroll
        for (int i = 0; i < 4; ++i) {
            const int r  = srow + 16 * i;
            const int rr = (r < rem) ? r : (rem - 1);   // clamp: unconditional
            const float* xr = x + (size_t)s_perm[m0 + rr] * DD;
#pragma unroll
            for (int j = 0; j < 4; ++j)
                xv[i * 4 + j] = *(const floatx4*)(xr + skk + 128 * j);
        }

        // ---- (2) issue W DMA for steps 0..3 (8 calls in flight) ----
#pragma unroll
        for (int s = 0; s < 4; ++s) {
#pragma unroll
            for (int c = 0; c < 2; ++c)
                GLD16(wtile + (size_t)(c * 64 + wave * 8 + r8) * DD + s * BK + su,
                      (char*)(&Wl[s][0][0]) + c * 8192 + wave * 1024);
        }

        // ---- (3) cvt + swizzled Xs write (only live rows) ----
#pragma unroll
        for (int i = 0; i < 4; ++i) {
            const int r = srow + 16 * i;
            if (r < rem) {
                const int rs = (r & 7) << 3;
#pragma unroll
                for (int j = 0; j < 4; ++j) {
                    const int f0 = skk + 128 * j;
                    bf16x4 bv;
#pragma unroll
                    for (int q = 0; q < 4; ++q) bv[q] = (__bf16)xv[i * 4 + j][q];
                    *(bf16x4*)&Xs[r][f0 ^ rs] = bv;
                }
            }
        }
        LGKMCNT0; SBAR; SCHED0;           // Xs visible; 8 DMAs in flight

        // ---- (4) K loop: 16 steps, counted vmcnt, depth-4 prefetch ----
        floatx4 acc[4] = {{0,0,0,0},{0,0,0,0},{0,0,0,0},{0,0,0,0}};
        const int h = l16 & 7;
        const int wrow = wave * 16 + l16; // this wave's W rows (= out cols)

        auto compute = [&](int slot, int s) {
            const float* wl = &Wl[slot][0][0];
            const floatx4 blo = *(const floatx4*)(wl + wrow * BK + (((2 * kgrp)     ^ h) << 2));
            const floatx4 bhi = *(const floatx4*)(wl + wrow * BK + (((2 * kgrp + 1) ^ h) << 2));
            const bf16x8 bfrag = cvt8(blo, bhi);
            const int kb = (s * 32 + kgrp * 8) ^ (h << 3);
#pragma unroll
            for (int mc = 0; mc < 4; ++mc) {
                if (mc < nchunk) {
                    const bf16x8 afrag = *(const bf16x8*)&Xs[mc * 16 + l16][kb];
                    acc[mc] = __builtin_amdgcn_mfma_f32_16x16x32_bf16(
                                  afrag, bfrag, acc[mc], 0, 0, 0);
                }
            }
        };

        // steady state: wait step i (vmcnt 6), issue step i+4 into slot
        // (i+4)%5 = (i-1)%5 (freed: compute(i-1) finished before this
        // barrier), compute step i.  Fully unrolled -> constant slots.
#pragma unroll
        for (int i = 0; i < NSTEPS - 4; ++i) {
            VMCNT(6); SBAR; SCHED0;
            const int s    = i + 4;
            const int slot = s % NSLOT;
#pragma unroll
            for (int c = 0; c < 2; ++c)
                GLD16(wtile + (size_t)(c * 64 + wave * 8 + r8) * DD + s * BK + su,
                      (char*)(&Wl[slot][0][0]) + c * 8192 + wave * 1024);
            compute(i % NSLOT, i);
        }
        VMCNT(6); SBAR; SCHED0; compute((NSTEPS - 4) % NSLOT, NSTEPS - 4);
        VMCNT(4); SBAR; SCHED0; compute((NSTEPS - 3) % NSLOT, NSTEPS - 3);
        VMCNT(2); SBAR; SCHED0; compute((NSTEPS - 2) % NSLOT, NSTEPS - 2);
        VMCNT(0); SBAR; SCHED0; compute((NSTEPS - 1) % NSLOT, NSTEPS - 1);

        // ---- (5) epilogue: C/D layout col = lane&15, row = kgrp*4 + r ----
#pragma unroll
        for (int mc = 0; mc < 4; ++mc) {
            if (mc < nchunk) {
#pragma unroll
                for (int r = 0; r < 4; ++r) {
                    const int mloc = mc * 16 + kgrp * 4 + r;
                    if (mloc < rem)
                        out[(size_t)s_perm[m0 + mloc] * DD + ncol] =
                            acc[mc][r] + bias_v;
                }
            }
        }
        __syncthreads();                  // ring/Xs safe to reuse next tile
    }
}

extern "C" void kernel_launch(void* const* d_in, const int* in_sizes, int n_in,
                              void* d_out, int out_size, void* d_ws, size_t ws_size,
                              hipStream_t stream) {
    const float* x      = (const float*)d_in[0];
    const int*   act    = (const int*)  d_in[1];
    const float* weight = (const float*)d_in[2];
    const float* bias   = (const float*)d_in[3];
    float*       out    = (float*)d_out;

    dl_fused<<<dim3(NA, DD / BN), 512, 0, stream>>>(x, act, weight, bias, out);
}

// Round 10
// 19.309 us; speedup vs baseline: 1.0241x; 1.0241x over previous
//
#include <hip/hip_runtime.h>

// DiscreteLinear: z[b,i] = sum_j weight[a[b],i,j] * x[b,j] + bias[a[b],i]
// B=2048, A=64, D=512.
// R9 = R8 with the K-loop lockstep REMOVED.
// R8's depth increase was a no-op -> not DMA-latency-bound; the serializer
// was the per-step s_barrier convoy (needed only because waves DMA'd rows
// {wave*8..}+{64+wave*8..} but computed rows {wave*16..+15}). Now each wave
// DMAs exactly the 16 W-ring rows it computes -> no cross-wave dependency
// -> barrier-free K loop. vmcnt is per-wave, so each of the 8 waves runs
// its own depth-4 pipeline and the waves hide each other's stalls on the
// CU (wave-level overlap instead of 2 blocks/CU). Only 2 barriers/tile
// remain: Xs publish + tile-end reuse.

#define NA 64
#define DD 512
#define NB 2048
#define BN 128          // output cols per block
#define NW 8            // waves per block
#define BK 32           // fp32 k per ring step
#define NSTEPS 16       // DD / BK
#define NSLOT 5         // ring slots (depth-4 prefetch)

typedef __bf16  bf16x8  __attribute__((ext_vector_type(8)));
typedef __bf16  bf16x4  __attribute__((ext_vector_type(4)));
typedef float   floatx4 __attribute__((ext_vector_type(4)));

#define GLD16(g, l)                                                         \
  __builtin_amdgcn_global_load_lds(                                         \
      (const __attribute__((address_space(1))) void*)(g),                   \
      (__attribute__((address_space(3))) void*)(l), 16, 0, 0)
#define VMCNT(n) asm volatile("s_waitcnt vmcnt(" #n ")" ::: "memory")
#define LGKMCNT0 asm volatile("s_waitcnt lgkmcnt(0)" ::: "memory")
#define SBAR     __builtin_amdgcn_s_barrier()
#define SCHED0   __builtin_amdgcn_sched_barrier(0)

static __device__ inline bf16x8 cvt8(floatx4 lo, floatx4 hi) {
    bf16x8 r;
    r[0] = (__bf16)lo[0]; r[1] = (__bf16)lo[1];
    r[2] = (__bf16)lo[2]; r[3] = (__bf16)lo[3];
    r[4] = (__bf16)hi[0]; r[5] = (__bf16)hi[1];
    r[6] = (__bf16)hi[2]; r[7] = (__bf16)hi[3];
    return r;
}

__global__ __launch_bounds__(512, 1) void dl_fused(
        const float* __restrict__ x,
        const int*   __restrict__ act,
        const float* __restrict__ weight,
        const float* __restrict__ bias,
        float*       __restrict__ out)
{
    const int a    = blockIdx.x;         // linear id = a + 64*y -> XCD = a%8:
    const int tid  = threadIdx.x;        // the 4 col-tiles of an action share
    const int wave = tid >> 6;           // an XCD -> x/act L2 reuse
    const int lane = tid & 63;
    const int l16  = lane & 15;
    const int kgrp = lane >> 4;
    const int colbase = blockIdx.y * BN;
    const int ncol    = colbase + wave * 16 + l16;

    __shared__ int s_perm[NB];                          // 8 KB
    __shared__ int s_wcnt[NW];
    __shared__ __align__(16) __bf16 Xs[64][DD];         // 64 KB
    __shared__ __align__(16) float  Wl[NSLOT][BN][BK];  // 80 KB ring

    // ---- fused bucket: ballot-compact indices with act[i]==a ----
    const int ibase = wave * (NB / NW);
    int myact[NB / NW / 64];                            // 4, regs
    int wcnt = 0;
#pragma unroll
    for (int it = 0; it < NB / NW / 64; ++it) {
        myact[it] = act[ibase + it * 64 + lane];
        unsigned long long m = __ballot(myact[it] == a);
        wcnt += (int)__popcll(m);
    }
    if (lane == 0) s_wcnt[wave] = wcnt;
    __syncthreads();
    int cnt = 0, off = 0;
#pragma unroll
    for (int v = 0; v < NW; ++v) {
        const int c = s_wcnt[v];
        if (v < wave) off += c;
        cnt += c;
    }
    if (cnt == 0) return;
#pragma unroll
    for (int it = 0; it < NB / NW / 64; ++it) {
        unsigned long long m = __ballot(myact[it] == a);
        if (myact[it] == a) {
            int pos = off + (int)__popcll(m & ((1ull << lane) - 1ull));
            s_perm[pos] = ibase + it * 64 + lane;
        }
        off += (int)__popcll(m);
    }
    __syncthreads();                      // publish s_perm

    const float  bias_v = bias[(size_t)a * DD + ncol];
    const float* wtile  = weight + (size_t)a * DD * DD + (size_t)colbase * DD;

    // DMA decomposition: wave owns ring rows [wave*16, wave*16+16) — the
    // same rows its compute reads (barrier-free invariant). Per call
    // c in {0,1}: rows wave*16 + c*8 + r8; XOR row-chunk source swizzle
    // (rule #21: linear LDS dest + inverse-swizzled global source).
    const int r8 = lane >> 3;             // row-within-8 group, 0..7
    const int su = ((lane & 7) ^ r8) << 2;// swizzled float offset in 128B chunk
    const int srow = tid >> 5;            // x staging: 0..15
    const int skk  = (tid & 31) << 2;     // 32 lanes x float4 per row

    for (int m0 = 0; m0 < cnt; m0 += 64) {
        const int rem    = min(cnt - m0, 64);
        const int nchunk = (rem + 15) >> 4;

        // ---- (1) issue x loads (OLDER than DMA: consume waits vmcnt(8)) ----
        floatx4 xv[16];
#pragma unroll
        for (int i = 0; i < 4; ++i) {
            const int r  = srow + 16 * i;
            const int rr = (r < rem) ? r : (rem - 1);   // clamp: unconditional
            const float* xr = x + (size_t)s_perm[m0 + rr] * DD;
#pragma unroll
            for (int j = 0; j < 4; ++j)
                xv[i * 4 + j] = *(const floatx4*)(xr + skk + 128 * j);
        }

        // ---- (2) issue this wave's W DMA for steps 0..3 (8 calls) ----
#pragma unroll
        for (int s = 0; s < 4; ++s) {
#pragma unroll
            for (int c = 0; c < 2; ++c)
                GLD16(wtile + (size_t)(wave * 16 + c * 8 + r8) * DD + s * BK + su,
                      (char*)(&Wl[s][wave * 16 + c * 8][0]));
        }

        // ---- (3) cvt + swizzled Xs write (only live rows) ----
#pragma unroll
        for (int i = 0; i < 4; ++i) {
            const int r = srow + 16 * i;
            if (r < rem) {
                const int rs = (r & 7) << 3;
#pragma unroll
                for (int j = 0; j < 4; ++j) {
                    const int f0 = skk + 128 * j;
                    bf16x4 bv;
#pragma unroll
                    for (int q = 0; q < 4; ++q) bv[q] = (__bf16)xv[i * 4 + j][q];
                    *(bf16x4*)&Xs[r][f0 ^ rs] = bv;
                }
            }
        }
        LGKMCNT0; SBAR;                   // Xs visible to all waves

        // ---- (4) K loop: barrier-free, per-wave depth-4 counted vmcnt ----
        floatx4 acc[4] = {{0,0,0,0},{0,0,0,0},{0,0,0,0},{0,0,0,0}};
        const int h = l16 & 7;
        const int wrow = wave * 16 + l16; // this wave's W rows (= out cols)

        auto compute = [&](int slot, int s) {
            const float* wl = &Wl[slot][0][0];
            const floatx4 blo = *(const floatx4*)(wl + wrow * BK + (((2 * kgrp)     ^ h) << 2));
            const floatx4 bhi = *(const floatx4*)(wl + wrow * BK + (((2 * kgrp + 1) ^ h) << 2));
            const bf16x8 bfrag = cvt8(blo, bhi);
            const int kb = (s * 32 + kgrp * 8) ^ (h << 3);
#pragma unroll
            for (int mc = 0; mc < 4; ++mc) {
                if (mc < nchunk) {
                    const bf16x8 afrag = *(const bf16x8*)&Xs[mc * 16 + l16][kb];
                    acc[mc] = __builtin_amdgcn_mfma_f32_16x16x32_bf16(
                                  afrag, bfrag, acc[mc], 0, 0, 0);
                }
            }
        };

        // steady state (no barrier): wait own step i (vmcnt 6), issue own
        // step i+4 into slot (i+4)%5 = (i-1)%5 (this wave consumed it at
        // iteration i-1), compute step i. Fully unrolled -> constant slots.
#pragma unroll
        for (int i = 0; i < NSTEPS - 4; ++i) {
            VMCNT(6); SCHED0;
            const int s    = i + 4;
            const int slot = s % NSLOT;
#pragma unroll
            for (int c = 0; c < 2; ++c)
                GLD16(wtile + (size_t)(wave * 16 + c * 8 + r8) * DD + s * BK + su,
                      (char*)(&Wl[slot][wave * 16 + c * 8][0]));
            compute(i % NSLOT, i);
        }
        VMCNT(6); SCHED0; compute((NSTEPS - 4) % NSLOT, NSTEPS - 4);
        VMCNT(4); SCHED0; compute((NSTEPS - 3) % NSLOT, NSTEPS - 3);
        VMCNT(2); SCHED0; compute((NSTEPS - 2) % NSLOT, NSTEPS - 2);
        VMCNT(0); SCHED0; compute((NSTEPS - 1) % NSLOT, NSTEPS - 1);

        // ---- (5) epilogue: C/D layout col = lane&15, row = kgrp*4 + r ----
#pragma unroll
        for (int mc = 0; mc < 4; ++mc) {
            if (mc < nchunk) {
#pragma unroll
                for (int r = 0; r < 4; ++r) {
                    const int mloc = mc * 16 + kgrp * 4 + r;
                    if (mloc < rem)
                        out[(size_t)s_perm[m0 + mloc] * DD + ncol] =
                            acc[mc][r] + bias_v;
                }
            }
        }
        __syncthreads();                  // ring/Xs safe to reuse next tile
    }
}

extern "C" void kernel_launch(void* const* d_in, const int* in_sizes, int n_in,
                              void* d_out, int out_size, void* d_ws, size_t ws_size,
                              hipStream_t stream) {
    const float* x      = (const float*)d_in[0];
    const int*   act    = (const int*)  d_in[1];
    const float* weight = (const float*)d_in[2];
    const float* bias   = (const float*)d_in[3];
    float*       out    = (float*)d_out;

    dl_fused<<<dim3(NA, DD / BN), 512, 0, stream>>>(x, act, weight, bias, out);
}